// Round 6
// baseline (1125.093 us; speedup 1.0000x reference)
//
#include <hip/hip_runtime.h>
#include <hip/hip_fp16.h>

static constexpr int INF = 16;
static constexpr int HID = 64;
static constexpr int NC  = 32;
static constexpr int SHIFT = 8;        // 256 destination nodes per bucket
static constexpr int BK    = 256;
static constexpr int NBMAX = 512;      // max buckets (n <= 131072)
static constexpr int SPLIT_IT = 32;    // edges per thread in k_split
static constexpr int SRC_BITS = 17;    // n <= 131072 -> src fits in 17 bits
static constexpr int SRC_MASK = (1 << SRC_BITS) - 1;
static constexpr int A1S = INF + 1;    // 17: padded LDS stride (bank-spread)
static constexpr int A2S = NC + 1;     // 33: padded LDS stride

struct alignas(8) half4 { __half2 lo, hi; };

__device__ __forceinline__ int clampi(int v, int n) {
    return v < 0 ? 0 : (v >= n ? n - 1 : v);
}

// ---- coarse histogram over destination buckets ----
__global__ __launch_bounds__(256) void k_hist1(const int* __restrict__ col, int E, int n,
                                               int* __restrict__ bcnt) {
    __shared__ int h[NBMAX];
    int t = threadIdx.x;
    for (int i = t; i < NBMAX; i += 256) h[i] = 0;
    __syncthreads();
    for (long long e = (long long)blockIdx.x * 256 + t; e < E; e += (long long)gridDim.x * 256)
        atomicAdd(&h[clampi(col[e], n) >> SHIFT], 1);
    __syncthreads();
    for (int i = t; i < NBMAX; i += 256)
        if (h[i]) atomicAdd(bcnt + i, h[i]);
}

// ---- exclusive scan of 512 bucket counts ----
__global__ __launch_bounds__(512) void k_bscan(const int* __restrict__ bcnt,
                                               int* __restrict__ boff, int* __restrict__ bcur) {
    __shared__ int sh[NBMAX];
    int t = threadIdx.x;
    int v = bcnt[t];
    sh[t] = v;
    __syncthreads();
    for (int off = 1; off < NBMAX; off <<= 1) {
        int a = (t >= off) ? sh[t - off] : 0;
        __syncthreads();
        sh[t] += a;
        __syncthreads();
    }
    int ex = sh[t] - v;
    boff[t] = ex;
    bcur[t] = ex;
    if (t == NBMAX - 1) boff[NBMAX] = sh[t];
}

// ---- multisplit: partition packed (ldst<<17|src) into bucket regions ----
__global__ __launch_bounds__(256) void k_split(const int* __restrict__ ei, int E, int n,
                                               int* __restrict__ bcur, int* __restrict__ pairs) {
    __shared__ int lh[NBMAX];
    __shared__ int base[NBMAX];
    int t = threadIdx.x;
    long long start = (long long)blockIdx.x * 256 * SPLIT_IT;
    int r[SPLIT_IT], c[SPLIT_IT];
    lh[t] = 0; lh[t + 256] = 0;
    __syncthreads();
#pragma unroll
    for (int i = 0; i < SPLIT_IT; ++i) {
        long long e = start + (long long)i * 256 + t;   // coalesced per i
        if (e < E) {
            r[i] = clampi(ei[e], n);
            c[i] = clampi(ei[E + e], n);
            atomicAdd(&lh[c[i] >> SHIFT], 1);
        } else {
            c[i] = -1;
        }
    }
    __syncthreads();
    for (int j = t; j < NBMAX; j += 256) {
        int cnt = lh[j];
        base[j] = cnt ? atomicAdd(bcur + j, cnt) : 0;
        lh[j] = 0;
    }
    __syncthreads();
#pragma unroll
    for (int i = 0; i < SPLIT_IT; ++i) {
        if (c[i] >= 0) {
            int b = c[i] >> SHIFT;
            int pos = base[b] + atomicAdd(&lh[b], 1);
            pairs[pos] = ((c[i] & (BK - 1)) << SRC_BITS) | r[i];
        }
    }
}

// ---- per-bucket: degrees -> dinv, then xs = fp16(x * dinv) for the bucket's nodes ----
__global__ __launch_bounds__(256) void k_prep(const int* __restrict__ pairs,
                                              const int* __restrict__ boff,
                                              const float* __restrict__ x,
                                              int n,
                                              float* __restrict__ dinv,
                                              __half2* __restrict__ xs) {
    __shared__ int h[BK];
    __shared__ float df[BK];
    int b = blockIdx.x, t = threadIdx.x;
    int bb = boff[b], be = boff[b + 1];
    h[t] = 0;
    __syncthreads();
    for (int i = bb + t; i < be; i += 256)
        atomicAdd(&h[pairs[i] >> SRC_BITS], 1);
    __syncthreads();
    int v = b * BK + t;
    float dv = 0.0f;
    if (v < n) {
        int d = h[t];
        dv = (d > 0) ? rsqrtf((float)d) : 0.0f;
        dinv[v] = dv;
    }
    df[t] = dv;
    __syncthreads();
    // cast this bucket's x rows: 256 nodes x 8 float2 each
    const float2* x2 = (const float2*)x;
    for (int idx = t; idx < BK * (INF / 2); idx += 256) {
        int vl = idx >> 3, fp = idx & 7;
        int gv = b * BK + vl;
        if (gv < n) {
            float2 val = x2[(long long)gv * (INF / 2) + fp];
            float d = df[vl];
            xs[(long long)gv * (INF / 2) + fp] = __floats2half2_rn(val.x * d, val.y * d);
        }
    }
}

// ---- layer-1 aggregation: edge-parallel, LDS f32 accumulate per bucket ----
__global__ __launch_bounds__(512) void k_aggX(const int* __restrict__ pairs,
                                              const int* __restrict__ boff,
                                              const float* __restrict__ dinv,
                                              const __half* __restrict__ xs,
                                              float* __restrict__ xa, int n) {
    __shared__ float acc[BK * A1S];     // 17.4 KB, padded stride
    int b = blockIdx.x, t = threadIdx.x;
    for (int i = t; i < BK * A1S; i += 512) acc[i] = 0.0f;
    __syncthreads();
    int bb = boff[b], be = boff[b + 1];
    int group = t >> 2, lane = t & 3;   // 128 groups x 4 lanes
    for (int e = bb + group; e < be; e += 128) {
        int p = pairs[e];
        int s = p & SRC_MASK;
        int ld = p >> SRC_BITS;
        half4 hv = *reinterpret_cast<const half4*>(xs + (long long)s * INF + lane * 4);
        float2 f0 = __half22float2(hv.lo);
        float2 f1 = __half22float2(hv.hi);
        float* a = acc + ld * A1S + lane * 4;
        atomicAdd(a + 0, f0.x);
        atomicAdd(a + 1, f0.y);
        atomicAdd(a + 2, f1.x);
        atomicAdd(a + 3, f1.y);
    }
    __syncthreads();
    for (int idx = t; idx < BK * INF; idx += 512) {
        int vl = idx >> 4, f = idx & 15;
        int gv = b * BK + vl;
        if (gv < n) xa[(long long)gv * INF + f] = acc[vl * A1S + f] * dinv[gv];
    }
}

// ---- fused MLP: h2h = fp16( (relu(xa@W1+b1)@W2) * dinv[v] ) ; 16 nodes/block ----
__global__ __launch_bounds__(256) void k_mlp(const float* __restrict__ xa,
                                             const float* __restrict__ W1,
                                             const float* __restrict__ b1,
                                             const float* __restrict__ W2,
                                             const float* __restrict__ dinv,
                                             __half2* __restrict__ h2h, int n) {
    __shared__ float W1l[INF * HID];
    __shared__ float W2l[HID * NC];
    __shared__ float b1l[HID];
    __shared__ float xal[16 * INF];
    __shared__ float hl[16 * HID];
    int t = threadIdx.x;
    for (int i = t; i < INF * HID; i += 256) W1l[i] = W1[i];
    for (int i = t; i < HID * NC; i += 256) W2l[i] = W2[i];
    if (t < HID) b1l[t] = b1[t];
    int base = blockIdx.x * 16;
    for (int i = t; i < 16 * INF; i += 256) {
        int r = i >> 4, k = i & 15;
        int v = base + r;
        xal[i] = (v < n) ? xa[(long long)v * INF + k] : 0.0f;
    }
    __syncthreads();
    for (int i = t; i < 16 * HID; i += 256) {
        int r = i >> 6, c = i & 63;
        float s = b1l[c];
#pragma unroll
        for (int k = 0; k < INF; ++k) s = fmaf(xal[r * INF + k], W1l[k * HID + c], s);
        hl[i] = fmaxf(s, 0.0f);
    }
    __syncthreads();
    {
        int r = t >> 4, cp = t & 15;
        int v = base + r;
        if (v < n) {
            int c0 = 2 * cp;
            float s0 = 0.f, s1 = 0.f;
#pragma unroll
            for (int k = 0; k < HID; ++k) {
                float hv = hl[r * HID + k];
                s0 = fmaf(hv, W2l[k * NC + c0], s0);
                s1 = fmaf(hv, W2l[k * NC + c0 + 1], s1);
            }
            float dv = dinv[v];
            h2h[(long long)v * (NC / 2) + cp] = __floats2half2_rn(s0 * dv, s1 * dv);
        }
    }
}

// ---- layer-2 aggregation: edge-parallel, LDS f32 accumulate per bucket ----
__global__ __launch_bounds__(512) void k_agg2(const int* __restrict__ pairs,
                                              const int* __restrict__ boff,
                                              const float* __restrict__ dinv,
                                              const __half* __restrict__ h2h,
                                              const float* __restrict__ b2,
                                              float* __restrict__ out, int n) {
    __shared__ float acc[BK * A2S];     // 33.8 KB, padded stride
    __shared__ float b2s[NC];
    int b = blockIdx.x, t = threadIdx.x;
    for (int i = t; i < BK * A2S; i += 512) acc[i] = 0.0f;
    if (t < NC) b2s[t] = b2[t];
    __syncthreads();
    int bb = boff[b], be = boff[b + 1];
    int group = t >> 3, lane = t & 7;   // 64 groups x 8 lanes
    for (int e = bb + group; e < be; e += 64) {
        int p = pairs[e];
        int s = p & SRC_MASK;
        int ld = p >> SRC_BITS;
        half4 hv = *reinterpret_cast<const half4*>(h2h + (long long)s * NC + lane * 4);
        float2 f0 = __half22float2(hv.lo);
        float2 f1 = __half22float2(hv.hi);
        float* a = acc + ld * A2S + lane * 4;
        atomicAdd(a + 0, f0.x);
        atomicAdd(a + 1, f0.y);
        atomicAdd(a + 2, f1.x);
        atomicAdd(a + 3, f1.y);
    }
    __syncthreads();
    for (int idx = t; idx < BK * NC; idx += 512) {
        int vl = idx >> 5, f = idx & 31;
        int gv = b * BK + vl;
        if (gv < n)
            out[(long long)gv * NC + f] = b2s[f] + acc[vl * A2S + f] * dinv[gv];
    }
}

extern "C" void kernel_launch(void* const* d_in, const int* in_sizes, int n_in,
                              void* d_out, int out_size, void* d_ws, size_t ws_size,
                              hipStream_t stream) {
    const float* x  = (const float*)d_in[0];
    const int*   ei = (const int*)d_in[1];   // int64 in reference -> pushed as int32
    const float* W1 = (const float*)d_in[2];
    const float* b1 = (const float*)d_in[3];
    const float* W2 = (const float*)d_in[4];
    const float* b2 = (const float*)d_in[5];
    float* out = (float*)d_out;

    const int n = in_sizes[0] / INF;
    const int E = in_sizes[1] / 2;
    const int NB = (n + BK - 1) / BK;        // 391 for n=100k (requires n <= 131072)

    // ws layout (4B units):
    //   pairs[E] | xs[8n] | xa[16n] | h2h[16n] | dinv[n] | bcnt[512] | boff[520] | bcur[512]
    //   ~29.3 MB total; no aliasing (pairs live through k_agg2)
    int*    pairs = (int*)d_ws;
    int*    p2    = pairs + (size_t)E;
    __half* xs    = (__half*)p2;
    float*  xa    = (float*)(p2 + (size_t)8 * n);
    __half* h2h   = (__half*)(p2 + (size_t)24 * n);
    float*  dinv  = (float*)(p2 + (size_t)40 * n);
    int*    bcnt  = (int*)(dinv + n);
    int*    boff  = bcnt + NBMAX;
    int*    bcur  = boff + (NBMAX + 8);

    hipMemsetAsync(bcnt, 0, NBMAX * sizeof(int), stream);

    k_hist1<<<512, 256, 0, stream>>>(ei + E, E, n, bcnt);
    k_bscan<<<1, NBMAX, 0, stream>>>(bcnt, boff, bcur);

    int splitBlocks = (int)((E + 256LL * SPLIT_IT - 1) / (256LL * SPLIT_IT));
    k_split<<<splitBlocks, 256, 0, stream>>>(ei, E, n, bcur, pairs);

    k_prep<<<NB, 256, 0, stream>>>(pairs, boff, x, n, dinv, (__half2*)xs);
    k_aggX<<<NB, 512, 0, stream>>>(pairs, boff, dinv, xs, xa, n);
    k_mlp<<<(n + 15) / 16, 256, 0, stream>>>(xa, W1, b1, W2, dinv, (__half2*)h2h, n);
    k_agg2<<<NB, 512, 0, stream>>>(pairs, boff, dinv, h2h, b2, out, n);
}

// Round 7
// 220.559 us; speedup vs baseline: 5.1011x; 5.1011x over previous
//
#include <hip/hip_runtime.h>
#include <hip/hip_fp16.h>

static constexpr int INF = 16;
static constexpr int HID = 64;
static constexpr int NC  = 32;
static constexpr int SHIFT = 9;      // bucket = dst >> 9 (512 nodes/bucket)
static constexpr int BK    = 512;    // nodes per bucket
static constexpr int NBMAX = 256;    // max buckets (n <= 131072)
static constexpr int SPLIT_IT = 32;  // edges per thread in k_split
static constexpr int SRC_BITS = 17;  // n <= 131072 -> src fits in 17 bits
static constexpr int SRC_MASK = (1 << SRC_BITS) - 1;

struct alignas(8) half4 { __half2 lo, hi; };

__device__ __forceinline__ int clampi(int v, int n) {
    return v < 0 ? 0 : (v >= n ? n - 1 : v);
}

// ---- coarse histogram over destination buckets ----
__global__ __launch_bounds__(256) void k_hist1(const int* __restrict__ col, int E, int n,
                                               int* __restrict__ bcnt) {
    __shared__ int h[NBMAX];
    int t = threadIdx.x;
    for (int i = t; i < NBMAX; i += 256) h[i] = 0;
    __syncthreads();
    for (long long e = (long long)blockIdx.x * 256 + t; e < E; e += (long long)gridDim.x * 256)
        atomicAdd(&h[clampi(col[e], n) >> SHIFT], 1);
    __syncthreads();
    for (int i = t; i < NBMAX; i += 256)
        if (h[i]) atomicAdd(bcnt + i, h[i]);
}

// ---- exclusive scan of bucket counts (single block) ----
__global__ __launch_bounds__(256) void k_bscan(const int* __restrict__ bcnt,
                                               int* __restrict__ boff, int* __restrict__ bcur) {
    __shared__ int sh[256];
    int t = threadIdx.x;
    int v = bcnt[t];
    sh[t] = v;
    __syncthreads();
    for (int off = 1; off < 256; off <<= 1) {
        int a = (t >= off) ? sh[t - off] : 0;
        __syncthreads();
        sh[t] += a;
        __syncthreads();
    }
    int ex = sh[t] - v;
    boff[t] = ex;
    bcur[t] = ex;
    if (t == 255) boff[256] = sh[t];
}

// ---- multisplit: partition packed ((dst&511)<<17 | src) into bucket regions ----
__global__ __launch_bounds__(256) void k_split(const int* __restrict__ ei, int E, int n,
                                               int* __restrict__ bcur, int* __restrict__ pairs) {
    __shared__ int lh[NBMAX];
    __shared__ int base[NBMAX];
    int t = threadIdx.x;
    long long start = (long long)blockIdx.x * 256 * SPLIT_IT;
    int r[SPLIT_IT], c[SPLIT_IT];
    lh[t] = 0;
    __syncthreads();
#pragma unroll
    for (int i = 0; i < SPLIT_IT; ++i) {
        long long e = start + (long long)i * 256 + t;   // coalesced per i
        if (e < E) {
            r[i] = clampi(ei[e], n);
            c[i] = clampi(ei[E + e], n);
            atomicAdd(&lh[c[i] >> SHIFT], 1);
        } else {
            c[i] = -1;
        }
    }
    __syncthreads();
    {
        int cnt = lh[t];
        base[t] = cnt ? atomicAdd(bcur + t, cnt) : 0;
        lh[t] = 0;
    }
    __syncthreads();
#pragma unroll
    for (int i = 0; i < SPLIT_IT; ++i) {
        if (c[i] >= 0) {
            int b = c[i] >> SHIFT;
            int pos = base[b] + atomicAdd(&lh[b], 1);
            pairs[pos] = ((c[i] & (BK - 1)) << SRC_BITS) | r[i];
        }
    }
}

// ---- fine pass: per-bucket deg/dinv/row_ptr + CSR src fill + fused x->fp16 cast ----
__global__ __launch_bounds__(256) void k_fine(const int* __restrict__ pairs,
                                              const int* __restrict__ boff,
                                              const float* __restrict__ x,
                                              int n, int E, int NB,
                                              float* __restrict__ dinv,
                                              int* __restrict__ row_ptr,
                                              int* __restrict__ src,
                                              __half2* __restrict__ xs) {
    __shared__ int h[BK];
    __shared__ int ex[BK];
    __shared__ int sh[256];
    __shared__ float df[BK];
    int b = blockIdx.x, t = threadIdx.x;
    int bb = boff[b], be = boff[b + 1];
    h[t] = 0; h[t + 256] = 0;
    __syncthreads();
    for (int i = bb + t; i < be; i += 256)
        atomicAdd(&h[pairs[i] >> SRC_BITS], 1);
    __syncthreads();
    int a0 = h[2 * t], a1 = h[2 * t + 1];
    int ps = a0 + a1;
    sh[t] = ps;
    __syncthreads();
    for (int off = 1; off < 256; off <<= 1) {
        int a = (t >= off) ? sh[t - off] : 0;
        __syncthreads();
        sh[t] += a;
        __syncthreads();
    }
    int ep = sh[t] - ps;
    ex[2 * t] = ep;
    ex[2 * t + 1] = ep + a0;
    __syncthreads();
    for (int j = t; j < BK; j += 256) {
        int v = b * BK + j;
        float dv = 0.0f;
        if (v < n) {
            int d = h[j];
            dv = (d > 0) ? rsqrtf((float)d) : 0.0f;
            dinv[v] = dv;
            row_ptr[v] = bb + ex[j];
        }
        df[j] = dv;
    }
    if (b == NB - 1 && t == 0) row_ptr[n] = E;
    for (int j = t; j < BK; j += 256) h[j] = bb + ex[j];   // cursors
    __syncthreads();
    for (int i = bb + t; i < be; i += 256) {
        int p = pairs[i];
        int pos = atomicAdd(&h[p >> SRC_BITS], 1);
        src[pos] = p & SRC_MASK;
    }
    // fused cast: xs[v] = fp16(x[v] * dinv[v]) for this bucket's 512 nodes
    const float2* x2 = (const float2*)x;
    for (int idx = t; idx < BK * (INF / 2); idx += 256) {
        int vl = idx >> 3, fp = idx & 7;
        int gv = b * BK + vl;
        if (gv < n) {
            float2 val = x2[(long long)gv * (INF / 2) + fp];
            float d = df[vl];
            xs[(long long)gv * (INF / 2) + fp] = __floats2half2_rn(val.x * d, val.y * d);
        }
    }
}

// ---- layer-1 gather: xa[v] = dinv[v]*sum xs[src] ; 4 lanes/node, 4x unrolled ----
__global__ __launch_bounds__(256) void k_aggX(const int* __restrict__ ptr,
                                              const int* __restrict__ src,
                                              const float* __restrict__ dinv,
                                              const __half* __restrict__ xs,
                                              float* __restrict__ xa, int n) {
    int t = threadIdx.x;
    int v = blockIdx.x * 64 + (t >> 2);
    int lane = t & 3;
    if (v >= n) return;
    int b = ptr[v], e = ptr[v + 1];
    float a0 = 0.f, a1 = 0.f, a2 = 0.f, a3 = 0.f;
    int i = b;
    for (; i + 4 <= e; i += 4) {
        int s0 = src[i], s1 = src[i + 1], s2 = src[i + 2], s3 = src[i + 3];
        half4 h0 = *reinterpret_cast<const half4*>(xs + (long long)s0 * INF + lane * 4);
        half4 h1 = *reinterpret_cast<const half4*>(xs + (long long)s1 * INF + lane * 4);
        half4 h2 = *reinterpret_cast<const half4*>(xs + (long long)s2 * INF + lane * 4);
        half4 h3 = *reinterpret_cast<const half4*>(xs + (long long)s3 * INF + lane * 4);
        float2 f;
        f = __half22float2(h0.lo); a0 += f.x; a1 += f.y;
        f = __half22float2(h0.hi); a2 += f.x; a3 += f.y;
        f = __half22float2(h1.lo); a0 += f.x; a1 += f.y;
        f = __half22float2(h1.hi); a2 += f.x; a3 += f.y;
        f = __half22float2(h2.lo); a0 += f.x; a1 += f.y;
        f = __half22float2(h2.hi); a2 += f.x; a3 += f.y;
        f = __half22float2(h3.lo); a0 += f.x; a1 += f.y;
        f = __half22float2(h3.hi); a2 += f.x; a3 += f.y;
    }
    for (; i < e; ++i) {
        int s = src[i];
        half4 hv = *reinterpret_cast<const half4*>(xs + (long long)s * INF + lane * 4);
        float2 f0 = __half22float2(hv.lo);
        float2 f1 = __half22float2(hv.hi);
        a0 += f0.x; a1 += f0.y; a2 += f1.x; a3 += f1.y;
    }
    float dv = dinv[v];
    float4 o = make_float4(a0 * dv, a1 * dv, a2 * dv, a3 * dv);
    *reinterpret_cast<float4*>(xa + (long long)v * INF + lane * 4) = o;
}

// ---- fused MLP: h2h = fp16( (relu(xa@W1+b1)@W2) * dinv[v] ) ; 16 nodes/block ----
__global__ __launch_bounds__(256) void k_mlp(const float* __restrict__ xa,
                                             const float* __restrict__ W1,
                                             const float* __restrict__ b1,
                                             const float* __restrict__ W2,
                                             const float* __restrict__ dinv,
                                             __half2* __restrict__ h2h, int n) {
    __shared__ float W1l[INF * HID];
    __shared__ float W2l[HID * NC];
    __shared__ float b1l[HID];
    __shared__ float xal[16 * INF];
    __shared__ float hl[16 * HID];
    int t = threadIdx.x;
    for (int i = t; i < INF * HID; i += 256) W1l[i] = W1[i];
    for (int i = t; i < HID * NC; i += 256) W2l[i] = W2[i];
    if (t < HID) b1l[t] = b1[t];
    int base = blockIdx.x * 16;
    for (int i = t; i < 16 * INF; i += 256) {
        int r = i >> 4, k = i & 15;
        int v = base + r;
        xal[i] = (v < n) ? xa[(long long)v * INF + k] : 0.0f;
    }
    __syncthreads();
    for (int i = t; i < 16 * HID; i += 256) {
        int r = i >> 6, c = i & 63;
        float s = b1l[c];
#pragma unroll
        for (int k = 0; k < INF; ++k) s = fmaf(xal[r * INF + k], W1l[k * HID + c], s);
        hl[i] = fmaxf(s, 0.0f);
    }
    __syncthreads();
    {
        int r = t >> 4, cp = t & 15;
        int v = base + r;
        if (v < n) {
            int c0 = 2 * cp;
            float s0 = 0.f, s1 = 0.f;
#pragma unroll
            for (int k = 0; k < HID; ++k) {
                float hv = hl[r * HID + k];
                s0 = fmaf(hv, W2l[k * NC + c0], s0);
                s1 = fmaf(hv, W2l[k * NC + c0 + 1], s1);
            }
            float dv = dinv[v];
            h2h[(long long)v * (NC / 2) + cp] = __floats2half2_rn(s0 * dv, s1 * dv);
        }
    }
}

// ---- layer-2 gather: out[v] = b2 + dinv[v]*sum h2h[src] ; 8 lanes/node, 4x unrolled ----
__global__ __launch_bounds__(256) void k_agg2(const int* __restrict__ ptr,
                                              const int* __restrict__ src,
                                              const float* __restrict__ dinv,
                                              const __half* __restrict__ h2h,
                                              const float* __restrict__ b2,
                                              float* __restrict__ out, int n) {
    int t = threadIdx.x;
    int v = blockIdx.x * 32 + (t >> 3);
    int lane = t & 7;
    if (v >= n) return;
    int b = ptr[v], e = ptr[v + 1];
    float a0 = 0.f, a1 = 0.f, a2 = 0.f, a3 = 0.f;
    int i = b;
    for (; i + 4 <= e; i += 4) {
        int s0 = src[i], s1 = src[i + 1], s2 = src[i + 2], s3 = src[i + 3];
        half4 h0 = *reinterpret_cast<const half4*>(h2h + (long long)s0 * NC + lane * 4);
        half4 h1 = *reinterpret_cast<const half4*>(h2h + (long long)s1 * NC + lane * 4);
        half4 h2 = *reinterpret_cast<const half4*>(h2h + (long long)s2 * NC + lane * 4);
        half4 h3 = *reinterpret_cast<const half4*>(h2h + (long long)s3 * NC + lane * 4);
        float2 f;
        f = __half22float2(h0.lo); a0 += f.x; a1 += f.y;
        f = __half22float2(h0.hi); a2 += f.x; a3 += f.y;
        f = __half22float2(h1.lo); a0 += f.x; a1 += f.y;
        f = __half22float2(h1.hi); a2 += f.x; a3 += f.y;
        f = __half22float2(h2.lo); a0 += f.x; a1 += f.y;
        f = __half22float2(h2.hi); a2 += f.x; a3 += f.y;
        f = __half22float2(h3.lo); a0 += f.x; a1 += f.y;
        f = __half22float2(h3.hi); a2 += f.x; a3 += f.y;
    }
    for (; i < e; ++i) {
        int s = src[i];
        half4 hv = *reinterpret_cast<const half4*>(h2h + (long long)s * NC + lane * 4);
        float2 f0 = __half22float2(hv.lo);
        float2 f1 = __half22float2(hv.hi);
        a0 += f0.x; a1 += f0.y; a2 += f1.x; a3 += f1.y;
    }
    float dv = dinv[v];
    const float4 bb = *reinterpret_cast<const float4*>(b2 + lane * 4);
    float4 o = make_float4(fmaf(a0, dv, bb.x), fmaf(a1, dv, bb.y),
                           fmaf(a2, dv, bb.z), fmaf(a3, dv, bb.w));
    *reinterpret_cast<float4*>(out + (long long)v * NC + lane * 4) = o;
}

extern "C" void kernel_launch(void* const* d_in, const int* in_sizes, int n_in,
                              void* d_out, int out_size, void* d_ws, size_t ws_size,
                              hipStream_t stream) {
    const float* x  = (const float*)d_in[0];
    const int*   ei = (const int*)d_in[1];   // int64 in reference -> pushed as int32
    const float* W1 = (const float*)d_in[2];
    const float* b1 = (const float*)d_in[3];
    const float* W2 = (const float*)d_in[4];
    const float* b2 = (const float*)d_in[5];
    float* out = (float*)d_out;

    const int n = in_sizes[0] / INF;
    const int E = in_sizes[1] / 2;
    const int NB = (n + BK - 1) / BK;        // 196 for n=100k

    // ws layout (4B units), no aliasing (~42.5 MB):
    //   pairs[E] | src[E] | xs[8n] | xa[16n] | h2h[16n] | dinv[n] | row_ptr[n+1] | bcnt|boff|bcur
    int*    pairs   = (int*)d_ws;
    int*    src     = pairs + (size_t)E;
    __half* xs      = (__half*)(src + E);
    float*  xa      = (float*)(src + E + (size_t)8 * n);
    __half* h2h     = (__half*)(src + E + (size_t)24 * n);
    float*  dinv    = (float*)(src + E + (size_t)40 * n);
    int*    row_ptr = (int*)(dinv + n);
    int*    bcnt    = row_ptr + (n + 1);
    int*    boff    = bcnt + NBMAX;
    int*    bcur    = boff + (NBMAX + 1);

    hipMemsetAsync(bcnt, 0, NBMAX * sizeof(int), stream);

    k_hist1<<<512, 256, 0, stream>>>(ei + E, E, n, bcnt);
    k_bscan<<<1, 256, 0, stream>>>(bcnt, boff, bcur);

    int splitBlocks = (int)((E + 256LL * SPLIT_IT - 1) / (256LL * SPLIT_IT));
    k_split<<<splitBlocks, 256, 0, stream>>>(ei, E, n, bcur, pairs);

    k_fine<<<NB, 256, 0, stream>>>(pairs, boff, x, n, E, NB, dinv, row_ptr, src, (__half2*)xs);

    k_aggX<<<(n + 63) / 64, 256, 0, stream>>>(row_ptr, src, dinv, xs, xa, n);
    k_mlp<<<(n + 15) / 16, 256, 0, stream>>>(xa, W1, b1, W2, dinv, (__half2*)h2h, n);
    k_agg2<<<(n + 31) / 32, 256, 0, stream>>>(row_ptr, src, dinv, h2h, b2, out, n);
}

// Round 8
// 191.877 us; speedup vs baseline: 5.8636x; 1.1495x over previous
//
#include <hip/hip_runtime.h>
#include <hip/hip_fp16.h>

static constexpr int INF = 16;
static constexpr int HID = 64;
static constexpr int NC  = 32;
static constexpr int SHIFT = 8;      // bucket = dst >> 8 (256 nodes/bucket)
static constexpr int BK    = 256;    // nodes per bucket
static constexpr int NBMAX = 512;    // max buckets (n <= 131072)
static constexpr int SPLIT_T  = 512; // threads in k_split
static constexpr int SPLIT_IT = 16;  // edges per thread in k_split
static constexpr int SRC_BITS = 17;  // n <= 131072 -> src fits in 17 bits
static constexpr int SRC_MASK = (1 << SRC_BITS) - 1;

struct alignas(8) half4 { __half2 lo, hi; };

__device__ __forceinline__ int clampi(int v, int n) {
    return v < 0 ? 0 : (v >= n ? n - 1 : v);
}

// ---- coarse histogram over destination buckets ----
__global__ __launch_bounds__(256) void k_hist1(const int* __restrict__ col, int E, int n,
                                               int* __restrict__ bcnt) {
    __shared__ int h[NBMAX];
    int t = threadIdx.x;
    for (int i = t; i < NBMAX; i += 256) h[i] = 0;
    __syncthreads();
    for (long long e = (long long)blockIdx.x * 256 + t; e < E; e += (long long)gridDim.x * 256)
        atomicAdd(&h[clampi(col[e], n) >> SHIFT], 1);
    __syncthreads();
    for (int i = t; i < NBMAX; i += 256)
        if (h[i]) atomicAdd(bcnt + i, h[i]);
}

// ---- exclusive scan of 512 bucket counts (single block) ----
__global__ __launch_bounds__(512) void k_bscan(const int* __restrict__ bcnt,
                                               int* __restrict__ boff, int* __restrict__ bcur) {
    __shared__ int sh[NBMAX];
    int t = threadIdx.x;
    int v = bcnt[t];
    sh[t] = v;
    __syncthreads();
    for (int off = 1; off < NBMAX; off <<= 1) {
        int a = (t >= off) ? sh[t - off] : 0;
        __syncthreads();
        sh[t] += a;
        __syncthreads();
    }
    int ex = sh[t] - v;
    boff[t] = ex;
    bcur[t] = ex;
    if (t == NBMAX - 1) boff[NBMAX] = sh[t];
}

// ---- multisplit: partition packed ((dst&255)<<17 | src) into bucket regions ----
__global__ __launch_bounds__(SPLIT_T) void k_split(const int* __restrict__ ei, int E, int n,
                                                   int* __restrict__ bcur, int* __restrict__ pairs) {
    __shared__ int lh[NBMAX];
    __shared__ int base[NBMAX];
    int t = threadIdx.x;
    long long start = (long long)blockIdx.x * SPLIT_T * SPLIT_IT;
    int r[SPLIT_IT], c[SPLIT_IT];
    for (int j = t; j < NBMAX; j += SPLIT_T) lh[j] = 0;
    __syncthreads();
#pragma unroll
    for (int i = 0; i < SPLIT_IT; ++i) {
        long long e = start + (long long)i * SPLIT_T + t;   // coalesced per i
        if (e < E) {
            r[i] = clampi(ei[e], n);
            c[i] = clampi(ei[E + e], n);
            atomicAdd(&lh[c[i] >> SHIFT], 1);
        } else {
            c[i] = -1;
        }
    }
    __syncthreads();
    for (int j = t; j < NBMAX; j += SPLIT_T) {
        int cnt = lh[j];
        base[j] = cnt ? atomicAdd(bcur + j, cnt) : 0;
        lh[j] = 0;
    }
    __syncthreads();
#pragma unroll
    for (int i = 0; i < SPLIT_IT; ++i) {
        if (c[i] >= 0) {
            int b = c[i] >> SHIFT;
            int pos = base[b] + atomicAdd(&lh[b], 1);
            pairs[pos] = ((c[i] & (BK - 1)) << SRC_BITS) | r[i];
        }
    }
}

// ---- fine pass (1024 thr): per-bucket deg/dinv/row_ptr + CSR fill + fused x cast ----
__global__ __launch_bounds__(1024) void k_fine(const int* __restrict__ pairs,
                                               const int* __restrict__ boff,
                                               const float* __restrict__ x,
                                               int n, int E, int NB,
                                               float* __restrict__ dinv,
                                               int* __restrict__ row_ptr,
                                               int* __restrict__ src,
                                               __half2* __restrict__ xs) {
    __shared__ int h[BK];     // histogram, later cursors
    __shared__ int sc[BK];    // scan workspace
    __shared__ float df[BK];
    int b = blockIdx.x, t = threadIdx.x;
    int bb = boff[b], be = boff[b + 1];
    if (t < BK) h[t] = 0;
    __syncthreads();
    for (int i = bb + t; i < be; i += 1024)
        atomicAdd(&h[pairs[i] >> SRC_BITS], 1);
    __syncthreads();
    // inclusive scan of 256 bins (threads >= BK idle but hit all barriers)
    int val = (t < BK) ? h[t] : 0;
    if (t < BK) sc[t] = val;
    __syncthreads();
    for (int off = 1; off < BK; off <<= 1) {
        int a = (t < BK && t >= off) ? sc[t - off] : 0;
        __syncthreads();
        if (t < BK) sc[t] += a;
        __syncthreads();
    }
    if (t < BK) {
        int ex = sc[t] - val;               // exclusive
        int v = b * BK + t;
        float dv = 0.0f;
        if (v < n) {
            dv = (val > 0) ? rsqrtf((float)val) : 0.0f;
            dinv[v] = dv;
            row_ptr[v] = bb + ex;
        }
        df[t] = dv;
        h[t] = bb + ex;                     // cursor
        if (b == NB - 1 && t == BK - 1) row_ptr[n] = E;
    }
    __syncthreads();
    for (int i = bb + t; i < be; i += 1024) {
        int p = pairs[i];
        int pos = atomicAdd(&h[p >> SRC_BITS], 1);
        src[pos] = p & SRC_MASK;
    }
    // fused cast: xs[v] = fp16(x[v] * dinv[v]) for this bucket's 256 nodes
    const float2* x2 = (const float2*)x;
    for (int idx = t; idx < BK * (INF / 2); idx += 1024) {
        int vl = idx >> 3, fp = idx & 7;
        int gv = b * BK + vl;
        if (gv < n) {
            float2 val2 = x2[(long long)gv * (INF / 2) + fp];
            float d = df[vl];
            xs[(long long)gv * (INF / 2) + fp] = __floats2half2_rn(val2.x * d, val2.y * d);
        }
    }
}

// ---- layer-1 gather: xa[v] = dinv[v]*sum xs[src] ; 4 lanes/node, 4x unrolled ----
__global__ __launch_bounds__(256) void k_aggX(const int* __restrict__ ptr,
                                              const int* __restrict__ src,
                                              const float* __restrict__ dinv,
                                              const __half* __restrict__ xs,
                                              float* __restrict__ xa, int n) {
    int t = threadIdx.x;
    int v = blockIdx.x * 64 + (t >> 2);
    int lane = t & 3;
    if (v >= n) return;
    int b = ptr[v], e = ptr[v + 1];
    float a0 = 0.f, a1 = 0.f, a2 = 0.f, a3 = 0.f;
    int i = b;
    for (; i + 4 <= e; i += 4) {
        int s0 = src[i], s1 = src[i + 1], s2 = src[i + 2], s3 = src[i + 3];
        half4 h0 = *reinterpret_cast<const half4*>(xs + (long long)s0 * INF + lane * 4);
        half4 h1 = *reinterpret_cast<const half4*>(xs + (long long)s1 * INF + lane * 4);
        half4 h2 = *reinterpret_cast<const half4*>(xs + (long long)s2 * INF + lane * 4);
        half4 h3 = *reinterpret_cast<const half4*>(xs + (long long)s3 * INF + lane * 4);
        float2 f;
        f = __half22float2(h0.lo); a0 += f.x; a1 += f.y;
        f = __half22float2(h0.hi); a2 += f.x; a3 += f.y;
        f = __half22float2(h1.lo); a0 += f.x; a1 += f.y;
        f = __half22float2(h1.hi); a2 += f.x; a3 += f.y;
        f = __half22float2(h2.lo); a0 += f.x; a1 += f.y;
        f = __half22float2(h2.hi); a2 += f.x; a3 += f.y;
        f = __half22float2(h3.lo); a0 += f.x; a1 += f.y;
        f = __half22float2(h3.hi); a2 += f.x; a3 += f.y;
    }
    for (; i < e; ++i) {
        int s = src[i];
        half4 hv = *reinterpret_cast<const half4*>(xs + (long long)s * INF + lane * 4);
        float2 f0 = __half22float2(hv.lo);
        float2 f1 = __half22float2(hv.hi);
        a0 += f0.x; a1 += f0.y; a2 += f1.x; a3 += f1.y;
    }
    float dv = dinv[v];
    float4 o = make_float4(a0 * dv, a1 * dv, a2 * dv, a3 * dv);
    *reinterpret_cast<float4*>(xa + (long long)v * INF + lane * 4) = o;
}

// ---- fused MLP: h2h = fp16( (relu(xa@W1+b1)@W2) * dinv[v] ) ; 16 nodes/block ----
__global__ __launch_bounds__(256) void k_mlp(const float* __restrict__ xa,
                                             const float* __restrict__ W1,
                                             const float* __restrict__ b1,
                                             const float* __restrict__ W2,
                                             const float* __restrict__ dinv,
                                             __half2* __restrict__ h2h, int n) {
    __shared__ float W1l[INF * HID];
    __shared__ float W2l[HID * NC];
    __shared__ float b1l[HID];
    __shared__ float xal[16 * INF];
    __shared__ float hl[16 * HID];
    int t = threadIdx.x;
    for (int i = t; i < INF * HID; i += 256) W1l[i] = W1[i];
    for (int i = t; i < HID * NC; i += 256) W2l[i] = W2[i];
    if (t < HID) b1l[t] = b1[t];
    int base = blockIdx.x * 16;
    for (int i = t; i < 16 * INF; i += 256) {
        int r = i >> 4, k = i & 15;
        int v = base + r;
        xal[i] = (v < n) ? xa[(long long)v * INF + k] : 0.0f;
    }
    __syncthreads();
    for (int i = t; i < 16 * HID; i += 256) {
        int r = i >> 6, c = i & 63;
        float s = b1l[c];
#pragma unroll
        for (int k = 0; k < INF; ++k) s = fmaf(xal[r * INF + k], W1l[k * HID + c], s);
        hl[i] = fmaxf(s, 0.0f);
    }
    __syncthreads();
    {
        int r = t >> 4, cp = t & 15;
        int v = base + r;
        if (v < n) {
            int c0 = 2 * cp;
            float s0 = 0.f, s1 = 0.f;
#pragma unroll
            for (int k = 0; k < HID; ++k) {
                float hv = hl[r * HID + k];
                s0 = fmaf(hv, W2l[k * NC + c0], s0);
                s1 = fmaf(hv, W2l[k * NC + c0 + 1], s1);
            }
            float dv = dinv[v];
            h2h[(long long)v * (NC / 2) + cp] = __floats2half2_rn(s0 * dv, s1 * dv);
        }
    }
}

// ---- layer-2 gather: out[v] = b2 + dinv[v]*sum h2h[src] ; 8 lanes/node, 4x unrolled ----
__global__ __launch_bounds__(256) void k_agg2(const int* __restrict__ ptr,
                                              const int* __restrict__ src,
                                              const float* __restrict__ dinv,
                                              const __half* __restrict__ h2h,
                                              const float* __restrict__ b2,
                                              float* __restrict__ out, int n) {
    int t = threadIdx.x;
    int v = blockIdx.x * 32 + (t >> 3);
    int lane = t & 7;
    if (v >= n) return;
    int b = ptr[v], e = ptr[v + 1];
    float a0 = 0.f, a1 = 0.f, a2 = 0.f, a3 = 0.f;
    int i = b;
    for (; i + 4 <= e; i += 4) {
        int s0 = src[i], s1 = src[i + 1], s2 = src[i + 2], s3 = src[i + 3];
        half4 h0 = *reinterpret_cast<const half4*>(h2h + (long long)s0 * NC + lane * 4);
        half4 h1 = *reinterpret_cast<const half4*>(h2h + (long long)s1 * NC + lane * 4);
        half4 h2 = *reinterpret_cast<const half4*>(h2h + (long long)s2 * NC + lane * 4);
        half4 h3 = *reinterpret_cast<const half4*>(h2h + (long long)s3 * NC + lane * 4);
        float2 f;
        f = __half22float2(h0.lo); a0 += f.x; a1 += f.y;
        f = __half22float2(h0.hi); a2 += f.x; a3 += f.y;
        f = __half22float2(h1.lo); a0 += f.x; a1 += f.y;
        f = __half22float2(h1.hi); a2 += f.x; a3 += f.y;
        f = __half22float2(h2.lo); a0 += f.x; a1 += f.y;
        f = __half22float2(h2.hi); a2 += f.x; a3 += f.y;
        f = __half22float2(h3.lo); a0 += f.x; a1 += f.y;
        f = __half22float2(h3.hi); a2 += f.x; a3 += f.y;
    }
    for (; i < e; ++i) {
        int s = src[i];
        half4 hv = *reinterpret_cast<const half4*>(h2h + (long long)s * NC + lane * 4);
        float2 f0 = __half22float2(hv.lo);
        float2 f1 = __half22float2(hv.hi);
        a0 += f0.x; a1 += f0.y; a2 += f1.x; a3 += f1.y;
    }
    float dv = dinv[v];
    const float4 bb = *reinterpret_cast<const float4*>(b2 + lane * 4);
    float4 o = make_float4(fmaf(a0, dv, bb.x), fmaf(a1, dv, bb.y),
                           fmaf(a2, dv, bb.z), fmaf(a3, dv, bb.w));
    *reinterpret_cast<float4*>(out + (long long)v * NC + lane * 4) = o;
}

extern "C" void kernel_launch(void* const* d_in, const int* in_sizes, int n_in,
                              void* d_out, int out_size, void* d_ws, size_t ws_size,
                              hipStream_t stream) {
    const float* x  = (const float*)d_in[0];
    const int*   ei = (const int*)d_in[1];   // int64 in reference -> pushed as int32
    const float* W1 = (const float*)d_in[2];
    const float* b1 = (const float*)d_in[3];
    const float* W2 = (const float*)d_in[4];
    const float* b2 = (const float*)d_in[5];
    float* out = (float*)d_out;

    const int n = in_sizes[0] / INF;
    const int E = in_sizes[1] / 2;
    const int NB = (n + BK - 1) / BK;        // 391 for n=100k

    // ws layout (4B units), no aliasing (~42.5 MB):
    //   pairs[E] | src[E] | xs[8n] | xa[16n] | h2h[16n] | dinv[n] | row_ptr[n+1] | bcnt|boff|bcur
    int*    pairs   = (int*)d_ws;
    int*    src     = pairs + (size_t)E;
    __half* xs      = (__half*)(src + E);
    float*  xa      = (float*)(src + E + (size_t)8 * n);
    __half* h2h     = (__half*)(src + E + (size_t)24 * n);
    float*  dinv    = (float*)(src + E + (size_t)40 * n);
    int*    row_ptr = (int*)(dinv + n);
    int*    bcnt    = row_ptr + (n + 1);
    int*    boff    = bcnt + NBMAX;
    int*    bcur    = boff + (NBMAX + 1);

    hipMemsetAsync(bcnt, 0, NBMAX * sizeof(int), stream);

    k_hist1<<<512, 256, 0, stream>>>(ei + E, E, n, bcnt);
    k_bscan<<<1, NBMAX, 0, stream>>>(bcnt, boff, bcur);

    int splitBlocks = (int)((E + (long long)SPLIT_T * SPLIT_IT - 1) / ((long long)SPLIT_T * SPLIT_IT));
    k_split<<<splitBlocks, SPLIT_T, 0, stream>>>(ei, E, n, bcur, pairs);

    k_fine<<<NB, 1024, 0, stream>>>(pairs, boff, x, n, E, NB, dinv, row_ptr, src, (__half2*)xs);

    k_aggX<<<(n + 63) / 64, 256, 0, stream>>>(row_ptr, src, dinv, xs, xa, n);
    k_mlp<<<(n + 15) / 16, 256, 0, stream>>>(xa, W1, b1, W2, dinv, (__half2*)h2h, n);
    k_agg2<<<(n + 31) / 32, 256, 0, stream>>>(row_ptr, src, dinv, h2h, b2, out, n);
}

// Round 9
// 181.453 us; speedup vs baseline: 6.2005x; 1.0574x over previous
//
#include <hip/hip_runtime.h>
#include <hip/hip_fp16.h>

static constexpr int INF = 16;
static constexpr int HID = 64;
static constexpr int NC  = 32;
static constexpr int SHIFT = 8;      // bucket = dst >> 8 (256 nodes/bucket)
static constexpr int BK    = 256;    // nodes per bucket
static constexpr int NBMAX = 512;    // max buckets (n <= 131072)
static constexpr int SPLIT_T  = 512; // threads in k_split
static constexpr int SPLIT_IT = 16;  // edges per thread in k_split
static constexpr int SRC_BITS = 17;  // n <= 131072 -> src fits in 17 bits
static constexpr int SRC_MASK = (1 << SRC_BITS) - 1;

struct alignas(8) half4 { __half2 lo, hi; };

__device__ __forceinline__ int clampi(int v, int n) {
    return v < 0 ? 0 : (v >= n ? n - 1 : v);
}

// ---- coarse histogram over destination buckets ----
__global__ __launch_bounds__(256) void k_hist1(const int* __restrict__ col, int E, int n,
                                               int* __restrict__ bcnt) {
    __shared__ int h[NBMAX];
    int t = threadIdx.x;
    for (int i = t; i < NBMAX; i += 256) h[i] = 0;
    __syncthreads();
    for (long long e = (long long)blockIdx.x * 256 + t; e < E; e += (long long)gridDim.x * 256)
        atomicAdd(&h[clampi(col[e], n) >> SHIFT], 1);
    __syncthreads();
    for (int i = t; i < NBMAX; i += 256)
        if (h[i]) atomicAdd(bcnt + i, h[i]);
}

// ---- exclusive scan of 512 bucket counts (single block) ----
__global__ __launch_bounds__(512) void k_bscan(const int* __restrict__ bcnt,
                                               int* __restrict__ boff, int* __restrict__ bcur) {
    __shared__ int sh[NBMAX];
    int t = threadIdx.x;
    int v = bcnt[t];
    sh[t] = v;
    __syncthreads();
    for (int off = 1; off < NBMAX; off <<= 1) {
        int a = (t >= off) ? sh[t - off] : 0;
        __syncthreads();
        sh[t] += a;
        __syncthreads();
    }
    int ex = sh[t] - v;
    boff[t] = ex;
    bcur[t] = ex;
    if (t == NBMAX - 1) boff[NBMAX] = sh[t];
}

// ---- multisplit: partition packed ((dst&255)<<17 | src) into bucket regions ----
__global__ __launch_bounds__(SPLIT_T) void k_split(const int* __restrict__ ei, int E, int n,
                                                   int* __restrict__ bcur, int* __restrict__ pairs) {
    __shared__ int lh[NBMAX];
    __shared__ int base[NBMAX];
    int t = threadIdx.x;
    long long start = (long long)blockIdx.x * SPLIT_T * SPLIT_IT;
    int r[SPLIT_IT], c[SPLIT_IT];
    for (int j = t; j < NBMAX; j += SPLIT_T) lh[j] = 0;
    __syncthreads();
#pragma unroll
    for (int i = 0; i < SPLIT_IT; ++i) {
        long long e = start + (long long)i * SPLIT_T + t;   // coalesced per i
        if (e < E) {
            r[i] = clampi(ei[e], n);
            c[i] = clampi(ei[E + e], n);
            atomicAdd(&lh[c[i] >> SHIFT], 1);
        } else {
            c[i] = -1;
        }
    }
    __syncthreads();
    for (int j = t; j < NBMAX; j += SPLIT_T) {
        int cnt = lh[j];
        base[j] = cnt ? atomicAdd(bcur + j, cnt) : 0;
        lh[j] = 0;
    }
    __syncthreads();
#pragma unroll
    for (int i = 0; i < SPLIT_IT; ++i) {
        if (c[i] >= 0) {
            int b = c[i] >> SHIFT;
            int pos = base[b] + atomicAdd(&lh[b], 1);
            pairs[pos] = ((c[i] & (BK - 1)) << SRC_BITS) | r[i];
        }
    }
}

// ---- fine pass (1024 thr): per-bucket deg/dinv/row_ptr + CSR fill + fused x cast ----
__global__ __launch_bounds__(1024) void k_fine(const int* __restrict__ pairs,
                                               const int* __restrict__ boff,
                                               const float* __restrict__ x,
                                               int n, int E, int NB,
                                               float* __restrict__ dinv,
                                               int* __restrict__ row_ptr,
                                               int* __restrict__ src,
                                               __half2* __restrict__ xs) {
    __shared__ int h[BK];     // histogram, later cursors
    __shared__ int sc[BK];    // scan workspace
    __shared__ float df[BK];
    int b = blockIdx.x, t = threadIdx.x;
    int bb = boff[b], be = boff[b + 1];
    if (t < BK) h[t] = 0;
    __syncthreads();
    for (int i = bb + t; i < be; i += 1024)
        atomicAdd(&h[pairs[i] >> SRC_BITS], 1);
    __syncthreads();
    int val = (t < BK) ? h[t] : 0;
    if (t < BK) sc[t] = val;
    __syncthreads();
    for (int off = 1; off < BK; off <<= 1) {
        int a = (t < BK && t >= off) ? sc[t - off] : 0;
        __syncthreads();
        if (t < BK) sc[t] += a;
        __syncthreads();
    }
    if (t < BK) {
        int ex = sc[t] - val;               // exclusive
        int v = b * BK + t;
        float dv = 0.0f;
        if (v < n) {
            dv = (val > 0) ? rsqrtf((float)val) : 0.0f;
            dinv[v] = dv;
            row_ptr[v] = bb + ex;
        }
        df[t] = dv;
        h[t] = bb + ex;                     // cursor
        if (b == NB - 1 && t == BK - 1) row_ptr[n] = E;
    }
    __syncthreads();
    for (int i = bb + t; i < be; i += 1024) {
        int p = pairs[i];
        int pos = atomicAdd(&h[p >> SRC_BITS], 1);
        src[pos] = p & SRC_MASK;
    }
    // fused cast: xs[v] = fp16(x[v] * dinv[v]) for this bucket's 256 nodes
    const float2* x2 = (const float2*)x;
    for (int idx = t; idx < BK * (INF / 2); idx += 1024) {
        int vl = idx >> 3, fp = idx & 7;
        int gv = b * BK + vl;
        if (gv < n) {
            float2 val2 = x2[(long long)gv * (INF / 2) + fp];
            float d = df[vl];
            xs[(long long)gv * (INF / 2) + fp] = __floats2half2_rn(val2.x * d, val2.y * d);
        }
    }
}

// ---- fused layer-1 gather + MLP: 64 nodes/block ----
// phase 1: xa = dinv[v]*sum xs[src]  (4 lanes/node, 8x unrolled, into LDS)
// phase 2: h2h = fp16( (relu(xa@W1+b1)@W2) * dinv[v] )
__global__ __launch_bounds__(256) void k_aggmlp(const int* __restrict__ ptr,
                                                const int* __restrict__ src,
                                                const float* __restrict__ dinv,
                                                const __half* __restrict__ xs,
                                                const float* __restrict__ W1,
                                                const float* __restrict__ b1,
                                                const float* __restrict__ W2,
                                                __half2* __restrict__ h2h, int n) {
    __shared__ float W1l[INF * HID];   // 4 KB
    __shared__ float W2l[HID * NC];    // 8 KB
    __shared__ float b1l[HID];
    __shared__ float xal[64 * INF];    // 4 KB
    __shared__ float hl[64 * HID];     // 16 KB
    int t = threadIdx.x;
    for (int i = t; i < INF * HID; i += 256) W1l[i] = W1[i];
    for (int i = t; i < HID * NC; i += 256) W2l[i] = W2[i];
    if (t < HID) b1l[t] = b1[t];

    int node = t >> 2, lane = t & 3;
    int v = blockIdx.x * 64 + node;
    float a0 = 0.f, a1 = 0.f, a2 = 0.f, a3 = 0.f;
    if (v < n) {
        int b = ptr[v], e = ptr[v + 1];
        int i = b;
        for (; i + 8 <= e; i += 8) {
            int s0 = src[i], s1 = src[i + 1], s2 = src[i + 2], s3 = src[i + 3];
            int s4 = src[i + 4], s5 = src[i + 5], s6 = src[i + 6], s7 = src[i + 7];
            half4 h0 = *reinterpret_cast<const half4*>(xs + (long long)s0 * INF + lane * 4);
            half4 h1 = *reinterpret_cast<const half4*>(xs + (long long)s1 * INF + lane * 4);
            half4 h2 = *reinterpret_cast<const half4*>(xs + (long long)s2 * INF + lane * 4);
            half4 h3 = *reinterpret_cast<const half4*>(xs + (long long)s3 * INF + lane * 4);
            half4 h4 = *reinterpret_cast<const half4*>(xs + (long long)s4 * INF + lane * 4);
            half4 h5 = *reinterpret_cast<const half4*>(xs + (long long)s5 * INF + lane * 4);
            half4 h6 = *reinterpret_cast<const half4*>(xs + (long long)s6 * INF + lane * 4);
            half4 h7 = *reinterpret_cast<const half4*>(xs + (long long)s7 * INF + lane * 4);
            float2 f;
            f = __half22float2(h0.lo); a0 += f.x; a1 += f.y;
            f = __half22float2(h0.hi); a2 += f.x; a3 += f.y;
            f = __half22float2(h1.lo); a0 += f.x; a1 += f.y;
            f = __half22float2(h1.hi); a2 += f.x; a3 += f.y;
            f = __half22float2(h2.lo); a0 += f.x; a1 += f.y;
            f = __half22float2(h2.hi); a2 += f.x; a3 += f.y;
            f = __half22float2(h3.lo); a0 += f.x; a1 += f.y;
            f = __half22float2(h3.hi); a2 += f.x; a3 += f.y;
            f = __half22float2(h4.lo); a0 += f.x; a1 += f.y;
            f = __half22float2(h4.hi); a2 += f.x; a3 += f.y;
            f = __half22float2(h5.lo); a0 += f.x; a1 += f.y;
            f = __half22float2(h5.hi); a2 += f.x; a3 += f.y;
            f = __half22float2(h6.lo); a0 += f.x; a1 += f.y;
            f = __half22float2(h6.hi); a2 += f.x; a3 += f.y;
            f = __half22float2(h7.lo); a0 += f.x; a1 += f.y;
            f = __half22float2(h7.hi); a2 += f.x; a3 += f.y;
        }
        for (; i < e; ++i) {
            int s = src[i];
            half4 hv = *reinterpret_cast<const half4*>(xs + (long long)s * INF + lane * 4);
            float2 f0 = __half22float2(hv.lo);
            float2 f1 = __half22float2(hv.hi);
            a0 += f0.x; a1 += f0.y; a2 += f1.x; a3 += f1.y;
        }
        float dv = dinv[v];
        a0 *= dv; a1 *= dv; a2 *= dv; a3 *= dv;
    }
    float* xr = xal + node * INF + lane * 4;
    xr[0] = a0; xr[1] = a1; xr[2] = a2; xr[3] = a3;
    __syncthreads();
    // hidden: 64 nodes x 64 hid, 16 per thread
    for (int i = t; i < 64 * HID; i += 256) {
        int r = i >> 6, c = i & 63;
        float s = b1l[c];
#pragma unroll
        for (int k = 0; k < INF; ++k) s = fmaf(xal[r * INF + k], W1l[k * HID + c], s);
        hl[i] = fmaxf(s, 0.0f);
    }
    __syncthreads();
    // out: 64 nodes x 16 half2, 4 per thread
    for (int i = t; i < 64 * (NC / 2); i += 256) {
        int r = i >> 4, cp = i & 15;
        int gv = blockIdx.x * 64 + r;
        if (gv < n) {
            int c0 = 2 * cp;
            float s0 = 0.f, s1 = 0.f;
#pragma unroll
            for (int k = 0; k < HID; ++k) {
                float hv = hl[r * HID + k];
                s0 = fmaf(hv, W2l[k * NC + c0], s0);
                s1 = fmaf(hv, W2l[k * NC + c0 + 1], s1);
            }
            float dv = dinv[gv];
            h2h[(long long)gv * (NC / 2) + cp] = __floats2half2_rn(s0 * dv, s1 * dv);
        }
    }
}

// ---- layer-2 gather: out[v] = b2 + dinv[v]*sum h2h[src] ; 8 lanes/node, 8x unrolled ----
__global__ __launch_bounds__(256) void k_agg2(const int* __restrict__ ptr,
                                              const int* __restrict__ src,
                                              const float* __restrict__ dinv,
                                              const __half* __restrict__ h2h,
                                              const float* __restrict__ b2,
                                              float* __restrict__ out, int n) {
    int t = threadIdx.x;
    int v = blockIdx.x * 32 + (t >> 3);
    int lane = t & 7;
    if (v >= n) return;
    int b = ptr[v], e = ptr[v + 1];
    float a0 = 0.f, a1 = 0.f, a2 = 0.f, a3 = 0.f;
    int i = b;
    for (; i + 8 <= e; i += 8) {
        int s0 = src[i], s1 = src[i + 1], s2 = src[i + 2], s3 = src[i + 3];
        int s4 = src[i + 4], s5 = src[i + 5], s6 = src[i + 6], s7 = src[i + 7];
        half4 h0 = *reinterpret_cast<const half4*>(h2h + (long long)s0 * NC + lane * 4);
        half4 h1 = *reinterpret_cast<const half4*>(h2h + (long long)s1 * NC + lane * 4);
        half4 h2 = *reinterpret_cast<const half4*>(h2h + (long long)s2 * NC + lane * 4);
        half4 h3 = *reinterpret_cast<const half4*>(h2h + (long long)s3 * NC + lane * 4);
        half4 h4 = *reinterpret_cast<const half4*>(h2h + (long long)s4 * NC + lane * 4);
        half4 h5 = *reinterpret_cast<const half4*>(h2h + (long long)s5 * NC + lane * 4);
        half4 h6 = *reinterpret_cast<const half4*>(h2h + (long long)s6 * NC + lane * 4);
        half4 h7 = *reinterpret_cast<const half4*>(h2h + (long long)s7 * NC + lane * 4);
        float2 f;
        f = __half22float2(h0.lo); a0 += f.x; a1 += f.y;
        f = __half22float2(h0.hi); a2 += f.x; a3 += f.y;
        f = __half22float2(h1.lo); a0 += f.x; a1 += f.y;
        f = __half22float2(h1.hi); a2 += f.x; a3 += f.y;
        f = __half22float2(h2.lo); a0 += f.x; a1 += f.y;
        f = __half22float2(h2.hi); a2 += f.x; a3 += f.y;
        f = __half22float2(h3.lo); a0 += f.x; a1 += f.y;
        f = __half22float2(h3.hi); a2 += f.x; a3 += f.y;
        f = __half22float2(h4.lo); a0 += f.x; a1 += f.y;
        f = __half22float2(h4.hi); a2 += f.x; a3 += f.y;
        f = __half22float2(h5.lo); a0 += f.x; a1 += f.y;
        f = __half22float2(h5.hi); a2 += f.x; a3 += f.y;
        f = __half22float2(h6.lo); a0 += f.x; a1 += f.y;
        f = __half22float2(h6.hi); a2 += f.x; a3 += f.y;
        f = __half22float2(h7.lo); a0 += f.x; a1 += f.y;
        f = __half22float2(h7.hi); a2 += f.x; a3 += f.y;
    }
    for (; i < e; ++i) {
        int s = src[i];
        half4 hv = *reinterpret_cast<const half4*>(h2h + (long long)s * NC + lane * 4);
        float2 f0 = __half22float2(hv.lo);
        float2 f1 = __half22float2(hv.hi);
        a0 += f0.x; a1 += f0.y; a2 += f1.x; a3 += f1.y;
    }
    float dv = dinv[v];
    const float4 bb = *reinterpret_cast<const float4*>(b2 + lane * 4);
    float4 o = make_float4(fmaf(a0, dv, bb.x), fmaf(a1, dv, bb.y),
                           fmaf(a2, dv, bb.z), fmaf(a3, dv, bb.w));
    *reinterpret_cast<float4*>(out + (long long)v * NC + lane * 4) = o;
}

extern "C" void kernel_launch(void* const* d_in, const int* in_sizes, int n_in,
                              void* d_out, int out_size, void* d_ws, size_t ws_size,
                              hipStream_t stream) {
    const float* x  = (const float*)d_in[0];
    const int*   ei = (const int*)d_in[1];   // int64 in reference -> pushed as int32
    const float* W1 = (const float*)d_in[2];
    const float* b1 = (const float*)d_in[3];
    const float* W2 = (const float*)d_in[4];
    const float* b2 = (const float*)d_in[5];
    float* out = (float*)d_out;

    const int n = in_sizes[0] / INF;
    const int E = in_sizes[1] / 2;
    const int NB = (n + BK - 1) / BK;        // 391 for n=100k

    // ws layout (4B units), no aliasing (~36 MB):
    //   pairs[E] | src[E] | xs[8n] | h2h[16n] | dinv[n] | row_ptr[n+1] | bcnt|boff|bcur
    int*    pairs   = (int*)d_ws;
    int*    src     = pairs + (size_t)E;
    __half* xs      = (__half*)(src + E);
    __half* h2h     = (__half*)(src + E + (size_t)8 * n);
    float*  dinv    = (float*)(src + E + (size_t)24 * n);
    int*    row_ptr = (int*)(dinv + n);
    int*    bcnt    = row_ptr + (n + 1);
    int*    boff    = bcnt + NBMAX;
    int*    bcur    = boff + (NBMAX + 1);

    hipMemsetAsync(bcnt, 0, NBMAX * sizeof(int), stream);

    k_hist1<<<512, 256, 0, stream>>>(ei + E, E, n, bcnt);
    k_bscan<<<1, NBMAX, 0, stream>>>(bcnt, boff, bcur);

    int splitBlocks = (int)((E + (long long)SPLIT_T * SPLIT_IT - 1) / ((long long)SPLIT_T * SPLIT_IT));
    k_split<<<splitBlocks, SPLIT_T, 0, stream>>>(ei, E, n, bcur, pairs);

    k_fine<<<NB, 1024, 0, stream>>>(pairs, boff, x, n, E, NB, dinv, row_ptr, src, (__half2*)xs);

    k_aggmlp<<<(n + 63) / 64, 256, 0, stream>>>(row_ptr, src, dinv, xs, W1, b1, W2,
                                                (__half2*)h2h, n);
    k_agg2<<<(n + 31) / 32, 256, 0, stream>>>(row_ptr, src, dinv, h2h, b2, out, n);
}